// Round 8
// baseline (127.139 us; speedup 1.0000x reference)
//
#include <hip/hip_runtime.h>

// SGCN fused: out[n,d,t,w] = sum_v (sum_c x[n,c,t,v]*W[c,d] + b[d]) * a[n,t,v,w]
// plus exact f32 copy of a into d_out second region.
// N=64, C_IN=C_OUT=64, T=300, V=25.
//
// Persistent streaming blocks: grid = 512 = 64 n x 8 t-slices (7x40t + 1x20t),
// exactly 2 blocks/CU (LDS 2x79KB). Each block loops chunks of 4 t:
//   scatter(k) -> barrier -> issue loads(k+1) -> compute(k) + stores.
// Double-buffered Xs/At, ONE barrier per chunk. All addressing hoisted.
// Wave wid: tl = wid>>1 (t in chunk), dh = wid&1 (32-row d-half).

typedef __attribute__((ext_vector_type(8))) short short8;
typedef __attribute__((ext_vector_type(4))) float f32x4;

#define XS_S 66
#define YS_S 36
#define AT_S 36
#define XBUF (4 * 32 * XS_S)   // 8448 ushorts
#define ABUF (4 * 32 * AT_S)   // 4608 ushorts

__device__ __forceinline__ unsigned short f2bf(float f) {
    unsigned int u = __builtin_bit_cast(unsigned int, f);
    return (unsigned short)((u + 0x7FFFu + ((u >> 16) & 1u)) >> 16);
}

__global__ __launch_bounds__(512, 4)
void sgcn_persist(const float* __restrict__ xg, const float* __restrict__ ag,
                  const float* __restrict__ Wg, const float* __restrict__ bg,
                  float* __restrict__ outg)
{
    __shared__ alignas(16) unsigned short Wt[64 * XS_S];   // W^T [d][c]
    __shared__ alignas(16) unsigned short Xs[2][XBUF];     // x [buf][tl][v][c]
    __shared__ alignas(16) unsigned short At[2][ABUF];     // a^T [buf][tl][w][v]
    __shared__ alignas(16) unsigned short Ys[8 * 32 * YS_S]; // y [wave][dl][v]

    const int tid  = threadIdx.x;
    const int wid  = tid >> 6;
    const int lane = tid & 63;
    const int q    = lane >> 4;   // 0..3
    const int lo   = lane & 15;   // 0..15

    const int bid = blockIdx.x;
    const int n   = bid >> 3;
    const int s   = bid & 7;          // t-slice
    const int t0  = 40 * s;           // 0,40,...,280 (mult of 4 -> aligned)
    const int nch = (s < 7) ? 10 : 5; // slice len 40 or 20, chunks of 4 t

    // ---- per-thread scatter constants (hoisted: loop-invariant) ----
    int xgoff[4], offx[4][4];
    bool vxm[4];
#pragma unroll
    for (int m = 0; m < 4; ++m) {
        const int f = tid + 512 * m;          // 0..2047, valid < 1600
        vxm[m] = (m < 3) || (tid < 64);
        const int c = f / 25, j = f % 25;
        xgoff[m] = c * 7500 + 4 * j;
#pragma unroll
        for (int i = 0; i < 4; ++i) {
            const int e = 4 * j + i;          // 0..99 within 4-t row
            offx[m][i] = (e / 25) * (32 * XS_S) + (e % 25) * XS_S + c;
        }
    }
    int agoff[2], offa[2][4];
    bool vam[2];
#pragma unroll
    for (int m = 0; m < 2; ++m) {
        const int af = tid + 512 * m;         // valid < 625
        vam[m] = (m < 1) || (tid < 113);
        agoff[m] = 4 * af;
#pragma unroll
        for (int i = 0; i < 4; ++i) {
            const int e = 4 * af + i;         // (t,v,w) flat in 4-t window
            const int tc = e / 625, r = e % 625;
            offa[m][i] = tc * (32 * AT_S) + (r % 25) * AT_S + (r / 25);
        }
    }

    // ---- chunk-0 loads (issued before W staging so they fly early) ----
    const float* xb = xg + n * 480000 + t0 * 25;
    const float* ab = ag + n * 187500 + t0 * 625;
    float*       ao = outg + 30720000 + n * 187500 + t0 * 625;

    f32x4 xv[4], av[2];
#pragma unroll
    for (int m = 0; m < 4; ++m) if (vxm[m]) xv[m] = *(const f32x4*)(xb + xgoff[m]);
#pragma unroll
    for (int m = 0; m < 2; ++m) if (vam[m]) av[m] = *(const f32x4*)(ab + agoff[m]);

    // ---- W load + stage; At pad columns (v=25..31) zero in BOTH buffers ----
    f32x4 wv[2];
#pragma unroll
    for (int m = 0; m < 2; ++m) wv[m] = *(const f32x4*)(Wg + 4 * (tid + 512 * m));

    if (tid < 256) {   // 2 buf x (4 tc x 32 w) rows
        unsigned short* ar = &At[tid >> 7][(tid & 127) * AT_S];
#pragma unroll
        for (int i = 25; i < 32; ++i) ar[i] = 0;
    }
#pragma unroll
    for (int m = 0; m < 2; ++m) {
        const int e0 = 4 * (tid + 512 * m);
#pragma unroll
        for (int i = 0; i < 4; ++i) {
            const int e = e0 + i;             // Wg flat = c*64 + d
            Wt[(e & 63) * XS_S + (e >> 6)] = f2bf(wv[m][i]);
        }
    }
    __syncthreads();   // Wt + At pads ready

    // ---- hoisted per-wave constants ----
    const int tl = wid >> 1;
    const int dh = wid & 1;
    const int d0 = 32 * dh;

    short8 wfrag[2][2];
#pragma unroll
    for (int mi = 0; mi < 2; ++mi)
#pragma unroll
        for (int ki = 0; ki < 2; ++ki)
            wfrag[mi][ki] = *(const short8*)&Wt[(d0 + 16 * mi + lo) * XS_S + 32 * ki + 8 * q];

    f32x4 bias[2];
#pragma unroll
    for (int mi = 0; mi < 2; ++mi)
#pragma unroll
        for (int r = 0; r < 4; ++r)
            bias[mi][r] = bg[d0 + 16 * mi + 4 * q + r];

    unsigned short* ys = Ys + wid * (32 * YS_S);
    const int outb = n * 480000;

    for (int kc = 0; kc < nch; ++kc) {
        unsigned short* xbuf = Xs[kc & 1];
        unsigned short* abuf = At[kc & 1];

        // ---- scatter chunk kc regs -> LDS (+ a f32 copy-out) ----
#pragma unroll
        for (int m = 0; m < 4; ++m) if (vxm[m]) {
#pragma unroll
            for (int i = 0; i < 4; ++i) xbuf[offx[m][i]] = f2bf(xv[m][i]);
        }
#pragma unroll
        for (int m = 0; m < 2; ++m) if (vam[m]) {
            *(f32x4*)(ao + agoff[m]) = av[m];
#pragma unroll
            for (int i = 0; i < 4; ++i) abuf[offa[m][i]] = f2bf(av[m][i]);
        }
        __syncthreads();   // staging visible; prev buffer's readers done

        // ---- issue next chunk's loads; they fly under this chunk's compute ----
        if (kc + 1 < nch) {
            xb += 100; ab += 2500; ao += 2500;
#pragma unroll
            for (int m = 0; m < 4; ++m) if (vxm[m]) xv[m] = *(const f32x4*)(xb + xgoff[m]);
#pragma unroll
            for (int m = 0; m < 2; ++m) if (vam[m]) av[m] = *(const f32x4*)(ab + agoff[m]);
        }

        // ---- step 1: y[dl,v] = b + sum_c W[c,d] x[c,v]  (M=32,N=32pad,K=64) ----
        const unsigned short* xs = xbuf + tl * (32 * XS_S);
        f32x4 accy[2][2];
#pragma unroll
        for (int mi = 0; mi < 2; ++mi) { accy[mi][0] = bias[mi]; accy[mi][1] = bias[mi]; }
#pragma unroll
        for (int ni = 0; ni < 2; ++ni)
#pragma unroll
            for (int ki = 0; ki < 2; ++ki) {
                const short8 bf = *(const short8*)&xs[(16 * ni + lo) * XS_S + 32 * ki + 8 * q];
#pragma unroll
                for (int mi = 0; mi < 2; ++mi)
                    accy[mi][ni] = __builtin_amdgcn_mfma_f32_16x16x32_bf16(
                        wfrag[mi][ki], bf, accy[mi][ni], 0, 0, 0);
            }

        // ---- y -> Ys[dl][v] (bf16, pad cols -> 0); per-wave private ----
#pragma unroll
        for (int mi = 0; mi < 2; ++mi)
#pragma unroll
            for (int ni = 0; ni < 2; ++ni) {
                const int v = 16 * ni + lo;
                const bool ok = (v < 25);
#pragma unroll
                for (int r = 0; r < 4; ++r)
                    ys[(16 * mi + 4 * q + r) * YS_S + v] =
                        ok ? f2bf(accy[mi][ni][r]) : (unsigned short)0;
            }

        // ---- step 2 (swapped): O^T[w,dl] = sum_v a^T[w,v] y[dl,v] ----
        const unsigned short* at = abuf + tl * (32 * AT_S);
        short8 afr[2];
#pragma unroll
        for (int mi = 0; mi < 2; ++mi)
            afr[mi] = *(const short8*)&at[(16 * mi + lo) * AT_S + 8 * q];
        short8 yfr[2];
#pragma unroll
        for (int dj = 0; dj < 2; ++dj)
            yfr[dj] = *(const short8*)&ys[(16 * dj + lo) * YS_S + 8 * q];

        f32x4 acco[2][2];
#pragma unroll
        for (int mi = 0; mi < 2; ++mi)
#pragma unroll
            for (int dj = 0; dj < 2; ++dj)
                acco[mi][dj] = f32x4{0.f, 0.f, 0.f, 0.f};
#pragma unroll
        for (int mi = 0; mi < 2; ++mi)
#pragma unroll
            for (int dj = 0; dj < 2; ++dj)
                acco[mi][dj] = __builtin_amdgcn_mfma_f32_16x16x32_bf16(
                    afr[mi], yfr[dj], acco[mi][dj], 0, 0, 0);

        // ---- store out[n,d,t,w]; lane's 4 regs = consecutive w ----
        const int t = t0 + 4 * kc + tl;
        float* op = outg + outb + t * 25;
#pragma unroll
        for (int dj = 0; dj < 2; ++dj) {
            const int dbase = (d0 + 16 * dj + lo) * 7500;
            *(f32x4*)(op + dbase + 4 * q) = acco[0][dj];          // w = 4q..4q+3
            if (q < 2)
                *(f32x4*)(op + dbase + 16 + 4 * q) = acco[1][dj]; // w = 16..23
            else if (q == 2)
                op[dbase + 24] = acco[1][dj][0];                  // w = 24
        }
    }
}

extern "C" void kernel_launch(void* const* d_in, const int* in_sizes, int n_in,
                              void* d_out, int out_size, void* d_ws, size_t ws_size,
                              hipStream_t stream) {
    const float* x = (const float*)d_in[0];
    const float* a = (const float*)d_in[1];
    const float* W = (const float*)d_in[2];
    const float* b = (const float*)d_in[3];
    float* out = (float*)d_out;
    // 512 persistent blocks = 64 n x 8 t-slices, exactly 2 blocks/CU
    hipLaunchKernelGGL(sgcn_persist, dim3(512), dim3(512), 0, stream,
                       x, a, W, b, out);
}

// Round 9
// 89.319 us; speedup vs baseline: 1.4234x; 1.4234x over previous
//
#include <hip/hip_runtime.h>

// SGCN fused: out[n,d,t,w] = sum_v (sum_c x[n,c,t,v]*W[c,d] + b[d]) * a[n,t,v,w]
// plus exact f32 copy of a into d_out second region.
// N=64, C_IN=C_OUT=64, T=300, V=25.
//
// R3 skeleton (best: 76.9us) + two changes:
//  (a) XCD-chunked block swizzle: gc = (bid&7)*600 + (bid>>3); each XCD owns
//      8 whole n's with t-chunks address-sequential -> a[n]/x reuse in ONE L2,
//      per-(n,d) out-write ranges assembled on one XCD.
//  (b) W^T pre-converted to bf16 in d_ws by a 1-block prep kernel; waves build
//      wfrag with 4 direct b128 loads (L2-hit). No W LDS staging (53->44.5KB).

typedef __attribute__((ext_vector_type(8))) short short8;
typedef __attribute__((ext_vector_type(4))) float f32x4;

#define XS_S 66   // Xs row stride (ushort)
#define YS_S 36   // Ys row stride
#define AT_S 36   // At row stride

__device__ __forceinline__ unsigned short f2bf(float f) {
    unsigned int u = __builtin_bit_cast(unsigned int, f);
    return (unsigned short)((u + 0x7FFFu + ((u >> 16) & 1u)) >> 16);
}

__global__ void sgcn_prep(const float* __restrict__ Wg, unsigned short* __restrict__ wt)
{
    // wt[d*64 + c] = bf16(Wg[c*64 + d]);  one block of 256 threads
    const int tid = threadIdx.x;
#pragma unroll
    for (int m = 0; m < 16; ++m) {
        const int e = tid + 256 * m;          // e = d*64 + c
        const int d = e >> 6, c = e & 63;
        wt[e] = f2bf(Wg[c * 64 + d]);
    }
}

__global__ __launch_bounds__(512, 6)
void sgcn_fused(const float* __restrict__ xg, const float* __restrict__ ag,
                const unsigned short* __restrict__ wt, const float* __restrict__ bg,
                float* __restrict__ outg)
{
    __shared__ alignas(16) unsigned short Xs[4 * 32 * XS_S];  // x [tl][v][c]
    __shared__ alignas(16) unsigned short Ys[8 * 32 * YS_S];  // y [wave][dl][v]
    __shared__ alignas(16) unsigned short At[4 * 32 * AT_S];  // a^T [tl][w][v]

    const int tid  = threadIdx.x;
    const int wid  = tid >> 6;
    const int lane = tid & 63;
    const int q    = lane >> 4;   // 0..3
    const int lo   = lane & 15;   // 0..15

    // ---- XCD-chunked swizzle: 4800 = 8 XCDs x 600 chunks ----
    const int bid = blockIdx.x;
    const int gc  = (bid & 7) * 600 + (bid >> 3);
    const int n   = gc / 75;
    const int t0  = (gc % 75) * 4;

    // ---------------- issue all global loads (independent, early) ----------
    // x slab: 64 c-rows x 100 floats (4 t's) = 1600 float4
    f32x4 xv[4];
    const long xbase = ((long)n * 64 * 300 + t0) * 25;
#pragma unroll
    for (int m = 0; m < 4; ++m) {
        const int f = tid + 512 * m;
        if (m < 3 || f < 1600) {
            const int c = f / 25, j = f % 25;
            xv[m] = *(const f32x4*)(xg + xbase + (long)c * 7500 + 4 * j);
        }
    }
    // a slab: 2500 floats = 625 float4
    f32x4 av[2];
    const long abase = ((long)n * 300 + t0) * 625;
#pragma unroll
    for (int m = 0; m < 2; ++m) {
        const int f = tid + 512 * m;
        if (m < 1 || f < 625)
            av[m] = *(const f32x4*)(ag + abase + 4 * f);
    }

    // ---------------- per-wave W fragments from prepped wt (L2-hit) --------
    const int tl = wid >> 1;
    const int dh = wid & 1;
    const int t  = t0 + tl;
    const int d0 = 32 * dh;

    short8 wfrag[2][2];
#pragma unroll
    for (int mi = 0; mi < 2; ++mi)
#pragma unroll
        for (int ki = 0; ki < 2; ++ki)
            wfrag[mi][ki] = *(const short8*)&wt[(d0 + 16 * mi + lo) * 64 + 32 * ki + 8 * q];

    f32x4 bias[2];
#pragma unroll
    for (int mi = 0; mi < 2; ++mi)
#pragma unroll
        for (int r = 0; r < 4; ++r)
            bias[mi][r] = bg[d0 + 16 * mi + 4 * q + r];

    // ---------------- zero At pad columns v=25..31 (K-dim of step 2) -------
    if (tid < 128) {   // 4 tl * 32 w-rows
        unsigned short* ar = &At[(tid >> 5) * (32 * AT_S) + (tid & 31) * AT_S];
#pragma unroll
        for (int i = 25; i < 32; ++i) ar[i] = 0;
    }

    // ---------------- scatter to LDS (bf16) --------------------------------
    // x -> Xs[tl][v][c]
#pragma unroll
    for (int m = 0; m < 4; ++m) {
        const int f = tid + 512 * m;
        if (m < 3 || f < 1600) {
            const int c = f / 25, j = f % 25;
#pragma unroll
            for (int i = 0; i < 4; ++i) {
                const int e = 4 * j + i;          // 0..99 within the 4-t row
                const int tc = e / 25, v = e % 25;
                Xs[tc * (32 * XS_S) + v * XS_S + c] = f2bf(xv[m][i]);
            }
        }
    }
    // a -> f32 copy to out + At[tl][w][v]
    {
        float* aout = outg + 30720000L + abase;
#pragma unroll
        for (int m = 0; m < 2; ++m) {
            const int f = tid + 512 * m;
            if (m < 1 || f < 625) {
                *(f32x4*)(aout + 4 * f) = av[m];
#pragma unroll
                for (int i = 0; i < 4; ++i) {
                    const int e = 4 * f + i;       // (t,v,w) flat
                    const int tc = e / 625, r = e % 625;
                    At[tc * (32 * AT_S) + (r % 25) * AT_S + (r / 25)] = f2bf(av[m][i]);
                }
            }
        }
    }
    __syncthreads();   // staging complete

    // ---------------- step 1: y[dl,v] = b + sum_c W[c,d] x[c,v] ------------
    // (M=32, N=32pad, K=64)
    const unsigned short* xs = Xs + tl * (32 * XS_S);
    f32x4 accy[2][2];
#pragma unroll
    for (int mi = 0; mi < 2; ++mi) { accy[mi][0] = bias[mi]; accy[mi][1] = bias[mi]; }
#pragma unroll
    for (int ni = 0; ni < 2; ++ni)
#pragma unroll
        for (int ki = 0; ki < 2; ++ki) {
            const short8 bf = *(const short8*)&xs[(16 * ni + lo) * XS_S + 32 * ki + 8 * q];
#pragma unroll
            for (int mi = 0; mi < 2; ++mi)
                accy[mi][ni] = __builtin_amdgcn_mfma_f32_16x16x32_bf16(
                    wfrag[mi][ki], bf, accy[mi][ni], 0, 0, 0);
        }

    // ---------------- y -> Ys[dl][v] (bf16, pad cols -> 0); wave-private ---
    unsigned short* ys = Ys + wid * (32 * YS_S);
#pragma unroll
    for (int mi = 0; mi < 2; ++mi)
#pragma unroll
        for (int ni = 0; ni < 2; ++ni) {
            const int v = 16 * ni + lo;
            const bool ok = (v < 25);
#pragma unroll
            for (int r = 0; r < 4; ++r)
                ys[(16 * mi + 4 * q + r) * YS_S + v] =
                    ok ? f2bf(accy[mi][ni][r]) : (unsigned short)0;
        }

    // ---------------- step 2 (swapped): O^T[w,dl] = sum_v a^T[w,v] y[dl,v] -
    const unsigned short* at = At + tl * (32 * AT_S);
    short8 afr[2];
#pragma unroll
    for (int mi = 0; mi < 2; ++mi)
        afr[mi] = *(const short8*)&at[(16 * mi + lo) * AT_S + 8 * q];
    short8 yfr[2];
#pragma unroll
    for (int dj = 0; dj < 2; ++dj)
        yfr[dj] = *(const short8*)&ys[(16 * dj + lo) * YS_S + 8 * q];

    f32x4 acco[2][2];
#pragma unroll
    for (int mi = 0; mi < 2; ++mi)
#pragma unroll
        for (int dj = 0; dj < 2; ++dj)
            acco[mi][dj] = f32x4{0.f, 0.f, 0.f, 0.f};
#pragma unroll
    for (int mi = 0; mi < 2; ++mi)
#pragma unroll
        for (int dj = 0; dj < 2; ++dj)
            acco[mi][dj] = __builtin_amdgcn_mfma_f32_16x16x32_bf16(
                afr[mi], yfr[dj], acco[mi][dj], 0, 0, 0);

    // ---------------- store out[n,d,t,w]; lane's 4 regs = consecutive w ----
    float* op = outg + ((long)n * 64 * 300 + t) * 25;
#pragma unroll
    for (int dj = 0; dj < 2; ++dj) {
        const long dbase = (long)(d0 + 16 * dj + lo) * 7500;
        *(f32x4*)(op + dbase + 4 * q) = acco[0][dj];          // w = 4q..4q+3
        if (q < 2)
            *(f32x4*)(op + dbase + 16 + 4 * q) = acco[1][dj]; // w = 16..23
        else if (q == 2)
            op[dbase + 24] = acco[1][dj][0];                  // w = 24
    }
}

extern "C" void kernel_launch(void* const* d_in, const int* in_sizes, int n_in,
                              void* d_out, int out_size, void* d_ws, size_t ws_size,
                              hipStream_t stream) {
    const float* x = (const float*)d_in[0];
    const float* a = (const float*)d_in[1];
    const float* W = (const float*)d_in[2];
    const float* b = (const float*)d_in[3];
    float* out = (float*)d_out;
    unsigned short* wt = (unsigned short*)d_ws;   // 4096 bf16 = 8KB

    hipLaunchKernelGGL(sgcn_prep, dim3(1), dim3(256), 0, stream, W, wt);
    hipLaunchKernelGGL(sgcn_fused, dim3(64 * 75), dim3(512), 0, stream,
                       x, a, wt, b, out);
}